// Round 2
// baseline (2577.553 us; speedup 1.0000x reference)
//
#include <hip/hip_runtime.h>
#include <stdint.h>
#include <stddef.h>

// Problem dims
#define B_  128
#define S_  48
#define E_  620
#define EP  640    // E padded to multiple of 32 (zeros)
#define H_  2400
#define N3  7200   // 3*H (r,i,n concatenated)
#define KH  2400
#define KA  7200   // logical K for recurrent GEMM: [h_hi | h_lo | h_hi]
#define ZSPLIT 6
#define KCHUNK 1216  // 38*32; 6*1216 = 7296 >= 7200

typedef __attribute__((ext_vector_type(8))) short   short8;
typedef __attribute__((ext_vector_type(8))) __bf16  bf16x8;
typedef __attribute__((ext_vector_type(4))) float   floatx4;

__device__ __forceinline__ short f2bf(float f) {
  union { float f; uint32_t u; } v; v.f = f;
  return (short)((v.u + 0x7fffu + ((v.u >> 16) & 1u)) >> 16);  // RNE
}
__device__ __forceinline__ float bf2f(short s) {
  union { uint32_t u; float f; } v; v.u = ((uint32_t)(uint16_t)s) << 16;
  return v.f;
}

// ---- x = bf16(emb[tokens]), padded [6144, 640] ----
__global__ void gather_cast_x(const int* __restrict__ tokens,
                              const float* __restrict__ emb,
                              short* __restrict__ xb) {
  int idx = blockIdx.x * 256 + threadIdx.x;       // over 6144*EP
  int m = idx / EP, c = idx - m * EP;
  float v = 0.f;
  if (c < E_) v = emb[(size_t)tokens[m] * E_ + c];
  xb[idx] = f2bf(v);
}

// ---- W_i = bf16 concat(W_ir,W_ii,W_in) [7200, 640]; bias concat [7200] ----
__global__ void convert_wi(const float* __restrict__ Wir, const float* __restrict__ Wii,
                           const float* __restrict__ Win,
                           const float* __restrict__ bir, const float* __restrict__ bii,
                           const float* __restrict__ bin,
                           short* __restrict__ Wi, float* __restrict__ bias) {
  int idx = blockIdx.x * 256 + threadIdx.x;       // over N3*EP
  int r = idx / EP, c = idx - r * EP;
  const float* W = (r < H_) ? Wir : (r < 2*H_ ? Wii : Win);
  int rr = (r < H_) ? r : (r < 2*H_ ? r - H_ : r - 2*H_);
  float v = (c < E_) ? W[(size_t)rr * E_ + c] : 0.f;
  Wi[idx] = f2bf(v);
  if (c == 0) {
    const float* bb = (r < H_) ? bir : (r < 2*H_ ? bii : bin);
    bias[r] = bb[rr];
  }
}

// ---- W2 = [W_hi | W_lo] of concat(W_hr,W_hi,W_hn): [7200, 4800] bf16 ----
__global__ void convert_wh(const float* __restrict__ Whr, const float* __restrict__ Whi,
                           const float* __restrict__ Whn, short* __restrict__ W2) {
  int idx = blockIdx.x * 256 + threadIdx.x;       // over N3*KH
  int r = idx / KH, c = idx - r * KH;
  const float* W = (r < H_) ? Whr : (r < 2*H_ ? Whi : Whn);
  int rr = (r < H_) ? r : (r < 2*H_ ? r - H_ : r - 2*H_);
  float w = W[(size_t)rr * KH + c];
  short hi = f2bf(w);
  short lo = f2bf(w - bf2f(hi));
  W2[(size_t)r * 4800 + c] = hi;
  W2[(size_t)r * 4800 + KH + c] = lo;
}

__global__ void init_h(float* __restrict__ h, short* __restrict__ hb) {
  int idx = blockIdx.x * 256 + threadIdx.x;       // over B_*KA
  hb[idx] = 0;
  if (idx < B_ * H_) h[idx] = 0.f;
}

// ---- Generic NT bf16 GEMM: C[m,n] = sum_k A[m,k]*B[n,k] (+bias[n]) ----
// Tile 128x128xBK32, 256 threads = 4 waves, 64x64 per wave via 16x16x32 MFMA.
// grid.z = K-split (kchunk); f32 partials to Cf + z*czstride, OR bf16 to Cb.
// bkwrap: B's k-index = (k < bkwrap ? k : k - bkwrap)  -> reuse B columns
// (realizes B' = [W_hi | W_hi | W_lo] over stored [W_hi | W_lo]).
__global__ __launch_bounds__(256) void gemm_nt(
    const short* __restrict__ A, int lda,
    const short* __restrict__ Bm, int ldb, int N,
    float* __restrict__ Cf, short* __restrict__ Cb, int ldc, long czstride,
    const float* __restrict__ bias, int K, int kchunk, int bkwrap)
{
  __shared__ short As[128][40];   // +8 shorts pad: breaks bank aliasing
  __shared__ short Bs[128][40];

  const int tid = threadIdx.x;
  const int m0 = blockIdx.x * 128;
  const int n0 = blockIdx.y * 128;
  const int z  = blockIdx.z;
  const int kb = z * kchunk;
  const int ke = min(K, kb + kchunk);

  const int lane = tid & 63;
  const int w  = tid >> 6;
  const int wm = (w >> 1) * 64;
  const int wn = (w & 1) * 64;
  const int fm = lane & 15;          // A-row / B-col within 16
  const int q8 = (lane >> 4) * 8;    // k sub-chunk

  floatx4 acc[4][4] = {};

  for (int k0 = kb; k0 < ke; k0 += 32) {
    const int bk0 = (k0 < bkwrap) ? k0 : k0 - bkwrap;
    #pragma unroll
    for (int i = 0; i < 2; ++i) {
      int c = tid + i * 256;         // 512 16B-chunks per tile
      int row = c >> 2;
      int kc = (c & 3) * 8;
      *(short8*)&As[row][kc] =
          *(const short8*)(A + (size_t)(m0 + row) * lda + k0 + kc);
      int rg = n0 + row; if (rg >= N) rg = N - 1;   // clamp ragged N reads
      *(short8*)&Bs[row][kc] =
          *(const short8*)(Bm + (size_t)rg * ldb + bk0 + kc);
    }
    __syncthreads();

    bf16x8 a[4], b[4];
    #pragma unroll
    for (int i = 0; i < 4; ++i) {
      a[i] = __builtin_bit_cast(bf16x8, *(short8*)&As[wm + i * 16 + fm][q8]);
      b[i] = __builtin_bit_cast(bf16x8, *(short8*)&Bs[wn + i * 16 + fm][q8]);
    }
    #pragma unroll
    for (int mf = 0; mf < 4; ++mf)
      #pragma unroll
      for (int nf = 0; nf < 4; ++nf)
        acc[mf][nf] = __builtin_amdgcn_mfma_f32_16x16x32_bf16(
            a[mf], b[nf], acc[mf][nf], 0, 0, 0);
    __syncthreads();
  }

  // C/D layout (m89-verified): col = lane&15, row = (lane>>4)*4 + reg
  const int col = lane & 15;
  const int qr = (lane >> 4) * 4;
  #pragma unroll
  for (int nf = 0; nf < 4; ++nf) {
    int n = n0 + wn + nf * 16 + col;
    if (n >= N) continue;
    float bv = bias ? bias[n] : 0.f;
    #pragma unroll
    for (int mf = 0; mf < 4; ++mf) {
      #pragma unroll
      for (int r = 0; r < 4; ++r) {
        int m = m0 + wm + mf * 16 + qr + r;
        float v = acc[mf][nf][r] + bv;
        if (Cf) Cf[(size_t)z * czstride + (size_t)m * ldc + n] = v;
        else    Cb[(size_t)m * ldc + n] = f2bf(v);
      }
    }
  }
}

// ---- GRU gate update for step t; h kept f32, A' = [h_hi|h_lo|h_hi] bf16 ----
__global__ void gate_step(const float* __restrict__ Gp, const short* __restrict__ gx,
                          float* __restrict__ h, short* __restrict__ hb,
                          const int* __restrict__ lengths, float* __restrict__ out,
                          int t)
{
  int idx = blockIdx.x * 256 + threadIdx.x;   // over B_*H_
  int b = idx / H_;
  int j = idx - b * H_;

  size_t rx = ((size_t)b * S_ + t) * N3;
  float xr = bf2f(gx[rx + j]);
  float xi = bf2f(gx[rx + H_ + j]);
  float xn = bf2f(gx[rx + 2 * H_ + j]);

  size_t gi = (size_t)b * N3;
  float Gr = 0.f, Gi = 0.f, Gn = 0.f;
  #pragma unroll
  for (int z = 0; z < ZSPLIT; ++z) {
    const float* Gz = Gp + (size_t)z * B_ * N3 + gi;
    Gr += Gz[j]; Gi += Gz[H_ + j]; Gn += Gz[2 * H_ + j];
  }

  float ho = h[idx];
  float r  = 1.f / (1.f + __expf(-(xr + Gr)));
  float ig = 1.f / (1.f + __expf(-(xi + Gi)));
  float n  = tanhf(xn + r * Gn);
  float hn = (1.f - ig) * n + ig * ho;

  h[idx] = hn;
  short hi16 = f2bf(hn);
  short lo16 = f2bf(hn - bf2f(hi16));
  size_t ra = (size_t)b * KA;
  hb[ra + j]            = hi16;
  hb[ra + H_ + j]       = lo16;
  hb[ra + 2 * H_ + j]   = hi16;

  int lc = lengths[b] - 1;
  lc = lc < 0 ? 0 : (lc > S_ - 1 ? S_ - 1 : lc);
  if (t == lc) out[idx] = hn;
}

extern "C" void kernel_launch(void* const* d_in, const int* in_sizes, int n_in,
                              void* d_out, int out_size, void* d_ws, size_t ws_size,
                              hipStream_t stream)
{
  const int*   tokens  = (const int*)d_in[0];
  const int*   lengths = (const int*)d_in[1];
  const float* emb = (const float*)d_in[2];
  const float* Wir = (const float*)d_in[3];
  const float* Wii = (const float*)d_in[4];
  const float* Win = (const float*)d_in[5];
  const float* bir = (const float*)d_in[6];
  const float* bii = (const float*)d_in[7];
  const float* bin = (const float*)d_in[8];
  const float* Whr = (const float*)d_in[9];
  const float* Whi = (const float*)d_in[10];
  const float* Whn = (const float*)d_in[11];
  float* out = (float*)d_out;

  char* ws = (char*)d_ws;
  size_t off = 0;
  auto alloc = [&](size_t bytes) {
    void* p = ws + off;
    off = (off + bytes + 255) & ~(size_t)255;
    return p;
  };
  short* xb   = (short*)alloc((size_t)(B_ * S_) * EP * 2);     //  7.9 MB
  short* Wi   = (short*)alloc((size_t)N3 * EP * 2);            //  9.2 MB
  short* W2   = (short*)alloc((size_t)N3 * 4800 * 2);          // 69.1 MB [W_hi|W_lo]
  float* bias = (float*)alloc((size_t)N3 * 4);
  short* gx   = (short*)alloc((size_t)(B_ * S_) * N3 * 2);     // 88.5 MB
  float* Gp   = (float*)alloc((size_t)ZSPLIT * B_ * N3 * 4);   // 22.1 MB
  float* h    = (float*)alloc((size_t)B_ * H_ * 4);
  short* hb   = (short*)alloc((size_t)B_ * KA * 2);            //  1.8 MB

  // conversions / gather (independent, cheap)
  gather_cast_x<<<(B_ * S_ * EP) / 256, 256, 0, stream>>>(tokens, emb, xb);
  convert_wi<<<(N3 * EP) / 256, 256, 0, stream>>>(Wir, Wii, Win, bir, bii, bin, Wi, bias);
  convert_wh<<<(N3 * KH) / 256, 256, 0, stream>>>(Whr, Whi, Whn, W2);
  init_h<<<(B_ * KA) / 256, 256, 0, stream>>>(h, hb);

  // Phase 1: gates_x = bf16( x @ W_i^T + b )   [6144 x 7200]
  gemm_nt<<<dim3(48, 57, 1), 256, 0, stream>>>(
      xb, EP, Wi, EP, N3, nullptr, gx, N3, 0, bias, EP, EP, 1 << 30);

  // Phase 2: 48 sequential GRU steps.
  // G = A'(128x7200) @ B'^T, A'=[h_hi|h_lo|h_hi], B'=[W_hi|W_hi|W_lo] via bkwrap.
  for (int t = 0; t < S_; ++t) {
    gemm_nt<<<dim3(1, 57, ZSPLIT), 256, 0, stream>>>(
        hb, KA, W2, 4800, N3, Gp, nullptr, N3, (long)B_ * N3,
        nullptr, KA, KCHUNK, KH);
    gate_step<<<(B_ * H_) / 256, 256, 0, stream>>>(Gp, gx, h, hb, lengths, out, t);
  }
}